// Round 1
// baseline (824.002 us; speedup 1.0000x reference)
//
#include <hip/hip_runtime.h>

// Problem constants (from reference)
#define NN 38332          // nodes
#define FF 544            // input features
#define CC 128            // channels
#define LL 4              // gcn layers
#define EE (NN*16)        // edges (613312)
#define PP 38333          // POI_LEN (output size)

static __device__ __forceinline__ float lrelu(float x) {
    return x >= 0.f ? x : 0.01f * x;
}

// ---------------------------------------------------------------------------
// Prep: val[i] = emb[poi[i/128]*128 + i%128]; deg init 1 (self loop); fill=0
// ---------------------------------------------------------------------------
__global__ __launch_bounds__(256) void k_prep(const float* __restrict__ feature,
                                              const float* __restrict__ emb,
                                              float* __restrict__ val,
                                              float* __restrict__ deg,
                                              int* __restrict__ fill, int n) {
    int i = blockIdx.x * 256 + threadIdx.x;
    if (i >= n) return;
    int row = i >> 7;            // i / 128
    int ch  = i & 127;
    int id  = (int)feature[row * FF];   // POI id stored as float in col 0
    val[i]  = emb[id * CC + ch];
    deg[i]  = 1.0f;              // self loop
    fill[i] = 0;
}

// deg[dst] += 1 for each edge
__global__ __launch_bounds__(256) void k_deg(const int* __restrict__ dst,
                                             float* __restrict__ deg, int e) {
    int i = blockIdx.x * 256 + threadIdx.x;
    if (i >= e) return;
    atomicAdd(&deg[dst[i]], 1.0f);
}

__global__ __launch_bounds__(256) void k_dinv(const float* __restrict__ deg,
                                              float* __restrict__ dinv, int n) {
    int i = blockIdx.x * 256 + threadIdx.x;
    if (i >= n) return;
    dinv[i] = rsqrtf(deg[i]);    // deg >= 1 always (self loop)
}

// Single-block exclusive scan of edge counts (deg-1) -> rowptr[0..n]
__global__ __launch_bounds__(1024) void k_scan(const float* __restrict__ deg,
                                               int* __restrict__ rowptr, int n) {
    __shared__ int sums[1024];
    int t = threadIdx.x;
    int chunk = (n + 1023) / 1024;
    int s = t * chunk;
    int e = min(n, s + chunk);
    int local = 0;
    for (int i = s; i < e; i++) local += (int)deg[i] - 1;
    sums[t] = local;
    __syncthreads();
    // Hillis-Steele inclusive scan
    for (int off = 1; off < 1024; off <<= 1) {
        int v = (t >= off) ? sums[t - off] : 0;
        __syncthreads();
        sums[t] += v;
        __syncthreads();
    }
    int run = (t == 0) ? 0 : sums[t - 1];
    for (int i = s; i < e; i++) {
        rowptr[i] = run;
        run += (int)deg[i] - 1;
    }
    if (t == 1023) rowptr[n] = run;   // = E
}

// Fill CSR: csr_src / csr_w grouped by dst
__global__ __launch_bounds__(256) void k_fill(const int* __restrict__ src,
                                              const int* __restrict__ dst,
                                              const float* __restrict__ dinv,
                                              const int* __restrict__ rowptr,
                                              int* __restrict__ fill,
                                              int* __restrict__ csr_src,
                                              float* __restrict__ csr_w, int e) {
    int i = blockIdx.x * 256 + threadIdx.x;
    if (i >= e) return;
    int d = dst[i], s = src[i];
    int pos = rowptr[d] + atomicAdd(&fill[d], 1);
    csr_src[pos] = s;
    csr_w[pos]   = dinv[s] * dinv[d];
}

// ---------------------------------------------------------------------------
// Tiled fp32 GEMM: H[n,128] = A[n,K] @ B[K,128].  BM=32, BN=128, BK=16.
// SUBST: substitute A[i,0] with val[i] (masked_scatter of embedding).
// ---------------------------------------------------------------------------
template <int K, bool SUBST>
__global__ __launch_bounds__(256) void k_gemm(const float* __restrict__ A, int lda,
                                              const float* __restrict__ val,
                                              const float* __restrict__ B,
                                              float* __restrict__ H, int n) {
    __shared__ float As[16][36];    // [k][m], padded
    __shared__ float Ws[16][128];
    const int t  = threadIdx.x;
    const int i0 = blockIdx.x * 32;
    const int tc = t & 31, tr = t >> 5;
    const int c0 = tc * 4, r0 = tr * 4;
    float acc[4][4] = {};

    for (int k0 = 0; k0 < K; k0 += 16) {
        // A tile: 32 rows x 16 k  (512 elems, 2/thread)
        #pragma unroll
        for (int j = 0; j < 2; j++) {
            int l = j * 256 + t;
            int m = l >> 4, k = l & 15;
            int i = i0 + m;
            float v = 0.f;
            if (i < n) {
                if (SUBST && (k0 + k) == 0) v = val[i];
                else v = A[(size_t)i * lda + k0 + k];
            }
            As[k][m] = v;
        }
        // B tile: 16 k x 128 c (2048 elems, 8/thread)
        #pragma unroll
        for (int j = 0; j < 8; j++) {
            int l = j * 256 + t;
            int k = l >> 7, c = l & 127;
            Ws[k][c] = B[(k0 + k) * CC + c];
        }
        __syncthreads();
        #pragma unroll
        for (int kk = 0; kk < 16; kk++) {
            float a[4], w[4];
            #pragma unroll
            for (int j = 0; j < 4; j++) a[j] = As[kk][r0 + j];
            #pragma unroll
            for (int j = 0; j < 4; j++) w[j] = Ws[kk][c0 + j];
            #pragma unroll
            for (int ri = 0; ri < 4; ri++)
                #pragma unroll
                for (int ci = 0; ci < 4; ci++)
                    acc[ri][ci] += a[ri] * w[ci];
        }
        __syncthreads();
    }
    #pragma unroll
    for (int ri = 0; ri < 4; ri++) {
        int i = i0 + r0 + ri;
        if (i < n) {
            float4 v = make_float4(acc[ri][0], acc[ri][1], acc[ri][2], acc[ri][3]);
            *(float4*)&H[(size_t)i * CC + c0] = v;
        }
    }
}

// ---------------------------------------------------------------------------
// Row gather (atomic-free scatter): one block (128 thr) per dst row.
// out = bias + self + sum(h[src]*w); MODE 0: lrelu(t)  MODE 1: lrelu(t)+t
// ---------------------------------------------------------------------------
template <int MODE>
__global__ __launch_bounds__(128) void k_row(const float* __restrict__ H,
                                             const int* __restrict__ rowptr,
                                             const int* __restrict__ csr_src,
                                             const float* __restrict__ csr_w,
                                             const float* __restrict__ dinv,
                                             const float* __restrict__ bias,
                                             float* __restrict__ X, int n) {
    const int i = blockIdx.x;
    const int c = threadIdx.x;
    const float di = dinv[i];
    float acc = bias[c] + H[(size_t)i * CC + c] * di * di;
    const int s = rowptr[i], e = rowptr[i + 1];
    __shared__ int   s_src[128];
    __shared__ float s_w[128];
    for (int base = s; base < e; base += 128) {
        int m = min(128, e - base);
        __syncthreads();
        if (c < m) { s_src[c] = csr_src[base + c]; s_w[c] = csr_w[base + c]; }
        __syncthreads();
        for (int j = 0; j < m; j++)
            acc += H[(size_t)s_src[j] * CC + c] * s_w[j];
    }
    float r = lrelu(acc);
    X[(size_t)i * CC + c] = MODE ? (r + acc) : r;
}

// x @ W_out  ([N,128] @ [128,1]) : one wave per row
__global__ __launch_bounds__(256) void k_wout(const float* __restrict__ x,
                                              const float* __restrict__ Wout,
                                              float* __restrict__ gpre, int n) {
    int gid  = blockIdx.x * 256 + threadIdx.x;
    int wid  = gid >> 6;
    int lane = threadIdx.x & 63;
    if (wid >= n) return;
    float p = x[(size_t)wid * CC + lane]      * Wout[lane]
            + x[(size_t)wid * CC + 64 + lane] * Wout[64 + lane];
    #pragma unroll
    for (int off = 32; off > 0; off >>= 1) p += __shfl_down(p, off, 64);
    if (lane == 0) gpre[wid] = p;
}

// scalar-channel row gather + lrelu -> g[N]
__global__ __launch_bounds__(256) void k_row1(const float* __restrict__ gpre,
                                              const int* __restrict__ rowptr,
                                              const int* __restrict__ csr_src,
                                              const float* __restrict__ csr_w,
                                              const float* __restrict__ dinv,
                                              const float* __restrict__ bout,
                                              float* __restrict__ g, int n) {
    int i = blockIdx.x * 256 + threadIdx.x;
    if (i >= n) return;
    float di = dinv[i];
    float acc = bout[0] + gpre[i] * di * di;
    int e1 = rowptr[i + 1];
    for (int e = rowptr[i]; e < e1; e++)
        acc += gpre[csr_src[e]] * csr_w[e];
    g[i] = lrelu(acc);
}

__global__ void k_hacc_init(const float* __restrict__ bfc1, float* __restrict__ hacc) {
    hacc[threadIdx.x] = bfc1[threadIdx.x];
}

// g[N] @ W_fc1[N,128] : block partial sums + atomic
__global__ __launch_bounds__(128) void k_fc1(const float* __restrict__ g,
                                             const float* __restrict__ Wfc1,
                                             float* __restrict__ hacc, int n) {
    int j = threadIdx.x;
    int nb = gridDim.x;
    int chunk = (n + nb - 1) / nb;
    int s = blockIdx.x * chunk;
    int e = min(n, s + chunk);
    float acc = 0.f;
    for (int i = s; i < e; i++)
        acc += g[i] * Wfc1[(size_t)i * CC + j];
    atomicAdd(&hacc[j], acc);
}

// relu(h) @ W_fc2[128,P] + b -> relu -> out[P]
__global__ __launch_bounds__(256) void k_fc2(const float* __restrict__ hacc,
                                             const float* __restrict__ Wfc2,
                                             const float* __restrict__ bfc2,
                                             float* __restrict__ out, int P) {
    __shared__ float sh[128];
    int t = threadIdx.x;
    if (t < 128) { float v = hacc[t]; sh[t] = v > 0.f ? v : 0.f; }
    __syncthreads();
    int k = blockIdx.x * 256 + t;
    if (k >= P) return;
    float acc = bfc2[k];
    #pragma unroll 8
    for (int j = 0; j < 128; j++)
        acc += sh[j] * Wfc2[(size_t)j * P + k];
    out[k] = acc > 0.f ? acc : 0.f;
}

// ---------------------------------------------------------------------------
extern "C" void kernel_launch(void* const* d_in, const int* in_sizes, int n_in,
                              void* d_out, int out_size, void* d_ws, size_t ws_size,
                              hipStream_t stream) {
    const float* feature = (const float*)d_in[0];
    // d_in[1] = mask (constant: col 0 true) -- unused
    const int*   eidx  = (const int*)d_in[2];
    const int*   e_src = eidx;
    const int*   e_dst = eidx + EE;
    const float* emb   = (const float*)d_in[3];
    const float* W_in  = (const float*)d_in[4];
    const float* b_in  = (const float*)d_in[5];
    const float* W_gcn = (const float*)d_in[6];
    const float* b_gcn = (const float*)d_in[7];
    const float* W_out = (const float*)d_in[8];
    const float* b_out = (const float*)d_in[9];
    const float* W_fc1 = (const float*)d_in[10];
    const float* b_fc1 = (const float*)d_in[11];
    const float* W_fc2 = (const float*)d_in[12];
    const float* b_fc2 = (const float*)d_in[13];
    float* out = (float*)d_out;

    // workspace carve-up (all 4-byte elems, 64-elem aligned)
    float* w = (float*)d_ws;
    size_t off = 0;
    auto take = [&](size_t elems) -> float* {
        float* p = w + off;
        off += (elems + 63) & ~(size_t)63;
        return p;
    };
    float* val     = take(NN);
    float* deg     = take(NN);
    float* dinv    = take(NN);
    int*   rowptr  = (int*)take(NN + 1);
    int*   fill    = (int*)take(NN);
    int*   csr_src = (int*)take(EE);
    float* csr_w   = take(EE);
    float* buf0    = take((size_t)NN * CC);   // x
    float* buf1    = take((size_t)NN * CC);   // h
    float* gpre    = take(NN);
    float* g       = take(NN);
    float* hacc    = take(128);
    (void)ws_size; (void)in_sizes; (void)n_in; (void)out_size;

    const int gN  = (NN + 255) / 256;
    const int gE  = (EE + 255) / 256;
    const int gBM = (NN + 31) / 32;

    // --- graph preprocessing: CSR by dst + symmetric norm ---
    k_prep<<<gN, 256, 0, stream>>>(feature, emb, val, deg, fill, NN);
    k_deg<<<gE, 256, 0, stream>>>(e_dst, deg, EE);
    k_dinv<<<gN, 256, 0, stream>>>(deg, dinv, NN);
    k_scan<<<1, 1024, 0, stream>>>(deg, rowptr, NN);
    k_fill<<<gE, 256, 0, stream>>>(e_src, e_dst, dinv, rowptr, fill,
                                   csr_src, csr_w, EE);

    // --- input GCN layer: x = lrelu(conv(emb_feature)) ---
    k_gemm<FF, true><<<gBM, 256, 0, stream>>>(feature, FF, val, W_in, buf1, NN);
    k_row<0><<<NN, 128, 0, stream>>>(buf1, rowptr, csr_src, csr_w, dinv, b_in,
                                     buf0, NN);

    // --- 4 GcnUnits: t = conv(x); x = lrelu(t) + t ---
    for (int l = 0; l < LL; l++) {
        k_gemm<CC, false><<<gBM, 256, 0, stream>>>(buf0, CC, nullptr,
                                                   W_gcn + (size_t)l * CC * CC,
                                                   buf1, NN);
        k_row<1><<<NN, 128, 0, stream>>>(buf1, rowptr, csr_src, csr_w, dinv,
                                         b_gcn + (size_t)l * CC, buf0, NN);
    }

    // --- output conv (C=1) ---
    k_wout<<<(NN * 64 + 255) / 256, 256, 0, stream>>>(buf0, W_out, gpre, NN);
    k_row1<<<gN, 256, 0, stream>>>(gpre, rowptr, csr_src, csr_w, dinv, b_out,
                                   g, NN);

    // --- FC head ---
    k_hacc_init<<<1, 128, 0, stream>>>(b_fc1, hacc);
    k_fc1<<<256, 128, 0, stream>>>(g, W_fc1, hacc, NN);
    k_fc2<<<(PP + 255) / 256, 256, 0, stream>>>(hacc, W_fc2, b_fc2, out, PP);
}

// Round 2
// 753.581 us; speedup vs baseline: 1.0934x; 1.0934x over previous
//
#include <hip/hip_runtime.h>

// Problem constants (from reference)
#define NN 38332          // nodes
#define FF 544            // input features
#define CC 128            // channels
#define LL 4              // gcn layers
#define EE (NN*16)        // edges (613312)
#define PP 38333          // POI_LEN (output size)

typedef __attribute__((ext_vector_type(8))) short short8v;
typedef __attribute__((ext_vector_type(4))) float floatx4;

static __device__ __forceinline__ float lrelu(float x) {
    return x >= 0.f ? x : 0.01f * x;
}

// fp32 -> bf16 round-to-nearest-even (bit trick)
static __device__ __forceinline__ short f2bf(float f) {
    unsigned u = __float_as_uint(f);
    unsigned r = (u + 0x7fffu + ((u >> 16) & 1u)) >> 16;
    return (short)r;
}
static __device__ __forceinline__ float bf2f(short s) {
    return __uint_as_float(((unsigned)(unsigned short)s) << 16);
}

// ---------------------------------------------------------------------------
// Prep: val[i] = emb[poi[i/128]*128 + i%128]; deg init 1 (self loop); fill=0
// (masked_scatter takes flattened emb_poi, first N elems -> val[i])
// ---------------------------------------------------------------------------
__global__ __launch_bounds__(256) void k_prep(const float* __restrict__ feature,
                                              const float* __restrict__ emb,
                                              float* __restrict__ val,
                                              float* __restrict__ deg,
                                              int* __restrict__ fill, int n) {
    int i = blockIdx.x * 256 + threadIdx.x;
    if (i >= n) return;
    int row = i >> 7;            // i / 128
    int ch  = i & 127;
    int id  = (int)feature[row * FF];   // POI id stored as float in col 0
    val[i]  = emb[id * CC + ch];
    deg[i]  = 1.0f;              // self loop
    fill[i] = 0;
}

// deg[dst] += 1 for each edge
__global__ __launch_bounds__(256) void k_deg(const int* __restrict__ dst,
                                             float* __restrict__ deg, int e) {
    int i = blockIdx.x * 256 + threadIdx.x;
    if (i >= e) return;
    atomicAdd(&deg[dst[i]], 1.0f);
}

__global__ __launch_bounds__(256) void k_dinv(const float* __restrict__ deg,
                                              float* __restrict__ dinv, int n) {
    int i = blockIdx.x * 256 + threadIdx.x;
    if (i >= n) return;
    dinv[i] = rsqrtf(deg[i]);    // deg >= 1 always (self loop)
}

// Single-block exclusive scan of edge counts (deg-1) -> rowptr[0..n]
__global__ __launch_bounds__(1024) void k_scan(const float* __restrict__ deg,
                                               int* __restrict__ rowptr, int n) {
    __shared__ int sums[1024];
    int t = threadIdx.x;
    int chunk = (n + 1023) / 1024;
    int s = t * chunk;
    int e = min(n, s + chunk);
    int local = 0;
    for (int i = s; i < e; i++) local += (int)deg[i] - 1;
    sums[t] = local;
    __syncthreads();
    for (int off = 1; off < 1024; off <<= 1) {
        int v = (t >= off) ? sums[t - off] : 0;
        __syncthreads();
        sums[t] += v;
        __syncthreads();
    }
    int run = (t == 0) ? 0 : sums[t - 1];
    for (int i = s; i < e; i++) {
        rowptr[i] = run;
        run += (int)deg[i] - 1;
    }
    if (t == 1023) rowptr[n] = run;   // = E
}

// Fill CSR: csr_src / csr_w grouped by dst
__global__ __launch_bounds__(256) void k_fill(const int* __restrict__ src,
                                              const int* __restrict__ dst,
                                              const float* __restrict__ dinv,
                                              const int* __restrict__ rowptr,
                                              int* __restrict__ fill,
                                              int* __restrict__ csr_src,
                                              float* __restrict__ csr_w, int e) {
    int i = blockIdx.x * 256 + threadIdx.x;
    if (i >= e) return;
    int d = dst[i], s = src[i];
    int pos = rowptr[d] + atomicAdd(&fill[d], 1);
    csr_src[pos] = s;
    csr_w[pos]   = dinv[s] * dinv[d];
}

// ---------------------------------------------------------------------------
// B split precompute: W[K][128] fp32 -> Bt_hi/Bt_lo[128][K] bf16 (transposed,
// n-major so MFMA B-frags (8 consecutive k per lane) are contiguous b128).
// ---------------------------------------------------------------------------
__global__ __launch_bounds__(256) void k_bsplit(const float* __restrict__ W,
                                                short* __restrict__ Bth,
                                                short* __restrict__ Btl, int K) {
    int idx = blockIdx.x * 256 + threadIdx.x;
    if (idx >= K * 128) return;
    int bn = idx / K, k = idx - bn * K;
    float w = W[k * CC + bn];
    short h = f2bf(w);
    Bth[idx] = h;
    Btl[idx] = f2bf(w - bf2f(h));
}

// ---------------------------------------------------------------------------
// MFMA GEMM: H[n,128] = A[n,K] @ B[K,128], bf16 2-term split (3 MFMA/prod).
// Block = 256 thr (4 waves), BM=64, BN=128, BK=32. mfma_f32_16x16x32_bf16.
// Wave w computes rows [m0=16w, m0+16) x all 128 cols (8 n-tiles).
// LDS rows padded to 40 shorts (80 B = 20 banks -> 2-way conflicts = free).
// SUBST: substitute A[i,0] with val[i] (masked_scatter of embedding).
// ---------------------------------------------------------------------------
template <int K, bool SUBST>
__global__ __launch_bounds__(256) void k_gemm_mfma(const float* __restrict__ A,
                                                   int lda,
                                                   const float* __restrict__ val,
                                                   const short* __restrict__ Bth,
                                                   const short* __restrict__ Btl,
                                                   float* __restrict__ H, int n) {
    __shared__ __align__(16) short Ah[64 * 40];
    __shared__ __align__(16) short Al[64 * 40];
    __shared__ __align__(16) short Bh[128 * 40];
    __shared__ __align__(16) short Bl[128 * 40];

    const int t    = threadIdx.x;
    const int i0   = blockIdx.x * 64;
    const int lane = t & 63;
    const int w    = t >> 6;
    const int fr   = lane & 15;    // m (A frag) / n (B frag) within tile
    const int sel  = lane >> 4;    // k-quad: k = sel*8 + j
    const int m0   = w * 16;

    floatx4 acc[8];
    #pragma unroll
    for (int j = 0; j < 8; j++) acc[j] = (floatx4){0.f, 0.f, 0.f, 0.f};

    const int ar = t >> 2, aseg = t & 3;   // A staging: row, 8-float segment

    for (int k0 = 0; k0 < K; k0 += 32) {
        // --- stage A tile 64x32 fp32 -> split bf16 (8 elems/thread) ---
        {
            int i = i0 + ar;
            float v[8];
            if (i < n) {
                const float* ap = A + (size_t)i * lda + k0 + aseg * 8;
                float4 p0 = *(const float4*)ap;
                float4 p1 = *(const float4*)(ap + 4);
                v[0] = p0.x; v[1] = p0.y; v[2] = p0.z; v[3] = p0.w;
                v[4] = p1.x; v[5] = p1.y; v[6] = p1.z; v[7] = p1.w;
                if (SUBST && k0 == 0 && aseg == 0) v[0] = val[i];
            } else {
                #pragma unroll
                for (int j = 0; j < 8; j++) v[j] = 0.f;
            }
            short8v hv, lv;
            #pragma unroll
            for (int j = 0; j < 8; j++) {
                short h = f2bf(v[j]);
                hv[j] = h;
                lv[j] = f2bf(v[j] - bf2f(h));
            }
            *(short8v*)&Ah[ar * 40 + aseg * 8] = hv;
            *(short8v*)&Al[ar * 40 + aseg * 8] = lv;
        }
        // --- stage B tile 128x32 bf16 hi/lo (2 x 16B chunks/thread/half) ---
        #pragma unroll
        for (int j = 0; j < 2; j++) {
            int c  = t + j * 256;
            int bn = c >> 2, bs = c & 3;
            const short* gh = Bth + (size_t)bn * K + k0 + bs * 8;
            const short* gl = Btl + (size_t)bn * K + k0 + bs * 8;
            *(short8v*)&Bh[bn * 40 + bs * 8] = *(const short8v*)gh;
            *(short8v*)&Bl[bn * 40 + bs * 8] = *(const short8v*)gl;
        }
        __syncthreads();

        // --- fragments + MFMA ---
        short8v ah = *(short8v*)&Ah[(m0 + fr) * 40 + sel * 8];
        short8v al = *(short8v*)&Al[(m0 + fr) * 40 + sel * 8];
        #pragma unroll
        for (int nt = 0; nt < 8; nt++) {
            short8v bh = *(short8v*)&Bh[(nt * 16 + fr) * 40 + sel * 8];
            short8v bl = *(short8v*)&Bl[(nt * 16 + fr) * 40 + sel * 8];
            acc[nt] = __builtin_amdgcn_mfma_f32_16x16x32_bf16(ah, bh, acc[nt], 0, 0, 0);
            acc[nt] = __builtin_amdgcn_mfma_f32_16x16x32_bf16(ah, bl, acc[nt], 0, 0, 0);
            acc[nt] = __builtin_amdgcn_mfma_f32_16x16x32_bf16(al, bh, acc[nt], 0, 0, 0);
        }
        __syncthreads();
    }

    // --- epilogue: C/D layout col=lane&15, row=(lane>>4)*4+reg ---
    #pragma unroll
    for (int nt = 0; nt < 8; nt++) {
        int col = nt * 16 + fr;
        #pragma unroll
        for (int r = 0; r < 4; r++) {
            int row = i0 + m0 + sel * 4 + r;
            if (row < n) H[(size_t)row * CC + col] = acc[nt][r];
        }
    }
}

// ---------------------------------------------------------------------------
// Row gather (atomic-free scatter): one block (128 thr) per dst row.
// out = bias + self + sum(h[src]*w); MODE 0: lrelu(t)  MODE 1: lrelu(t)+t
// ---------------------------------------------------------------------------
template <int MODE>
__global__ __launch_bounds__(128) void k_row(const float* __restrict__ H,
                                             const int* __restrict__ rowptr,
                                             const int* __restrict__ csr_src,
                                             const float* __restrict__ csr_w,
                                             const float* __restrict__ dinv,
                                             const float* __restrict__ bias,
                                             float* __restrict__ X, int n) {
    const int i = blockIdx.x;
    const int c = threadIdx.x;
    const float di = dinv[i];
    float acc = bias[c] + H[(size_t)i * CC + c] * di * di;
    const int s = rowptr[i], e = rowptr[i + 1];
    __shared__ int   s_src[128];
    __shared__ float s_w[128];
    for (int base = s; base < e; base += 128) {
        int m = min(128, e - base);
        __syncthreads();
        if (c < m) { s_src[c] = csr_src[base + c]; s_w[c] = csr_w[base + c]; }
        __syncthreads();
        for (int j = 0; j < m; j++)
            acc += H[(size_t)s_src[j] * CC + c] * s_w[j];
    }
    float r = lrelu(acc);
    X[(size_t)i * CC + c] = MODE ? (r + acc) : r;
}

// x @ W_out  ([N,128] @ [128,1]) : one wave per row
__global__ __launch_bounds__(256) void k_wout(const float* __restrict__ x,
                                              const float* __restrict__ Wout,
                                              float* __restrict__ gpre, int n) {
    int gid  = blockIdx.x * 256 + threadIdx.x;
    int wid  = gid >> 6;
    int lane = threadIdx.x & 63;
    if (wid >= n) return;
    float p = x[(size_t)wid * CC + lane]      * Wout[lane]
            + x[(size_t)wid * CC + 64 + lane] * Wout[64 + lane];
    #pragma unroll
    for (int off = 32; off > 0; off >>= 1) p += __shfl_down(p, off, 64);
    if (lane == 0) gpre[wid] = p;
}

// scalar-channel row gather + lrelu -> g[N]
__global__ __launch_bounds__(256) void k_row1(const float* __restrict__ gpre,
                                              const int* __restrict__ rowptr,
                                              const int* __restrict__ csr_src,
                                              const float* __restrict__ csr_w,
                                              const float* __restrict__ dinv,
                                              const float* __restrict__ bout,
                                              float* __restrict__ g, int n) {
    int i = blockIdx.x * 256 + threadIdx.x;
    if (i >= n) return;
    float di = dinv[i];
    float acc = bout[0] + gpre[i] * di * di;
    int e1 = rowptr[i + 1];
    for (int e = rowptr[i]; e < e1; e++)
        acc += gpre[csr_src[e]] * csr_w[e];
    g[i] = lrelu(acc);
}

__global__ void k_hacc_init(const float* __restrict__ bfc1, float* __restrict__ hacc) {
    hacc[threadIdx.x] = bfc1[threadIdx.x];
}

// g[N] @ W_fc1[N,128] : block partial sums + atomic
__global__ __launch_bounds__(128) void k_fc1(const float* __restrict__ g,
                                             const float* __restrict__ Wfc1,
                                             float* __restrict__ hacc, int n) {
    int j = threadIdx.x;
    int nb = gridDim.x;
    int chunk = (n + nb - 1) / nb;
    int s = blockIdx.x * chunk;
    int e = min(n, s + chunk);
    float acc = 0.f;
    for (int i = s; i < e; i++)
        acc += g[i] * Wfc1[(size_t)i * CC + j];
    atomicAdd(&hacc[j], acc);
}

// relu(h) @ W_fc2[128,P] + b -> relu -> out[P]
__global__ __launch_bounds__(256) void k_fc2(const float* __restrict__ hacc,
                                             const float* __restrict__ Wfc2,
                                             const float* __restrict__ bfc2,
                                             float* __restrict__ out, int P) {
    __shared__ float sh[128];
    int t = threadIdx.x;
    if (t < 128) { float v = hacc[t]; sh[t] = v > 0.f ? v : 0.f; }
    __syncthreads();
    int k = blockIdx.x * 256 + t;
    if (k >= P) return;
    float acc = bfc2[k];
    #pragma unroll 8
    for (int j = 0; j < 128; j++)
        acc += sh[j] * Wfc2[(size_t)j * P + k];
    out[k] = acc > 0.f ? acc : 0.f;
}

// ---------------------------------------------------------------------------
extern "C" void kernel_launch(void* const* d_in, const int* in_sizes, int n_in,
                              void* d_out, int out_size, void* d_ws, size_t ws_size,
                              hipStream_t stream) {
    const float* feature = (const float*)d_in[0];
    // d_in[1] = mask (constant: col 0 true) -- unused
    const int*   eidx  = (const int*)d_in[2];
    const int*   e_src = eidx;
    const int*   e_dst = eidx + EE;
    const float* emb   = (const float*)d_in[3];
    const float* W_in  = (const float*)d_in[4];
    const float* b_in  = (const float*)d_in[5];
    const float* W_gcn = (const float*)d_in[6];
    const float* b_gcn = (const float*)d_in[7];
    const float* W_out = (const float*)d_in[8];
    const float* b_out = (const float*)d_in[9];
    const float* W_fc1 = (const float*)d_in[10];
    const float* b_fc1 = (const float*)d_in[11];
    const float* W_fc2 = (const float*)d_in[12];
    const float* b_fc2 = (const float*)d_in[13];
    float* out = (float*)d_out;

    // workspace carve-up (float-granular, 64-elem = 256B aligned)
    float* w = (float*)d_ws;
    size_t off = 0;
    auto take = [&](size_t elems) -> float* {
        float* p = w + off;
        off += (elems + 63) & ~(size_t)63;
        return p;
    };
    float* val     = take(NN);
    float* deg     = take(NN);
    float* dinv    = take(NN);
    int*   rowptr  = (int*)take(NN + 1);
    int*   fill    = (int*)take(NN);
    int*   csr_src = (int*)take(EE);
    float* csr_w   = take(EE);
    float* buf0    = take((size_t)NN * CC);   // x
    float* buf1    = take((size_t)NN * CC);   // h
    float* gpre    = take(NN);
    float* g       = take(NN);
    float* hacc    = take(128);
    // bf16-split weight buffers (shorts; sizes in floats = shorts/2)
    short* bt_in_h  = (short*)take(FF * CC / 2);          // 544*128 shorts
    short* bt_in_l  = (short*)take(FF * CC / 2);
    short* bt_gcn_h = (short*)take((size_t)LL * CC * CC / 2);
    short* bt_gcn_l = (short*)take((size_t)LL * CC * CC / 2);
    (void)ws_size; (void)in_sizes; (void)n_in; (void)out_size;

    const int gN  = (NN + 255) / 256;
    const int gE  = (EE + 255) / 256;
    const int gBM = (NN + 63) / 64;

    // --- weight splits (once per call; B tiny) ---
    k_bsplit<<<(FF * CC + 255) / 256, 256, 0, stream>>>(W_in, bt_in_h, bt_in_l, FF);
    for (int l = 0; l < LL; l++)
        k_bsplit<<<(CC * CC + 255) / 256, 256, 0, stream>>>(
            W_gcn + (size_t)l * CC * CC,
            bt_gcn_h + (size_t)l * CC * CC, bt_gcn_l + (size_t)l * CC * CC, CC);

    // --- graph preprocessing: CSR by dst + symmetric norm ---
    k_prep<<<gN, 256, 0, stream>>>(feature, emb, val, deg, fill, NN);
    k_deg<<<gE, 256, 0, stream>>>(e_dst, deg, EE);
    k_dinv<<<gN, 256, 0, stream>>>(deg, dinv, NN);
    k_scan<<<1, 1024, 0, stream>>>(deg, rowptr, NN);
    k_fill<<<gE, 256, 0, stream>>>(e_src, e_dst, dinv, rowptr, fill,
                                   csr_src, csr_w, EE);

    // --- input GCN layer: x = lrelu(conv(emb_feature)) ---
    k_gemm_mfma<FF, true><<<gBM, 256, 0, stream>>>(feature, FF, val,
                                                   bt_in_h, bt_in_l, buf1, NN);
    k_row<0><<<NN, 128, 0, stream>>>(buf1, rowptr, csr_src, csr_w, dinv, b_in,
                                     buf0, NN);

    // --- 4 GcnUnits: t = conv(x); x = lrelu(t) + t ---
    for (int l = 0; l < LL; l++) {
        k_gemm_mfma<CC, false><<<gBM, 256, 0, stream>>>(
            buf0, CC, nullptr,
            bt_gcn_h + (size_t)l * CC * CC, bt_gcn_l + (size_t)l * CC * CC,
            buf1, NN);
        k_row<1><<<NN, 128, 0, stream>>>(buf1, rowptr, csr_src, csr_w, dinv,
                                         b_gcn + (size_t)l * CC, buf0, NN);
    }

    // --- output conv (C=1) ---
    k_wout<<<(NN * 64 + 255) / 256, 256, 0, stream>>>(buf0, W_out, gpre, NN);
    k_row1<<<gN, 256, 0, stream>>>(gpre, rowptr, csr_src, csr_w, dinv, b_out,
                                   g, NN);

    // --- FC head ---
    k_hacc_init<<<1, 128, 0, stream>>>(b_fc1, hacc);
    k_fc1<<<256, 128, 0, stream>>>(g, W_fc1, hacc, NN);
    k_fc2<<<(PP + 255) / 256, 256, 0, stream>>>(hacc, W_fc2, b_fc2, out, PP);
}